// Round 5
// baseline (283.733 us; speedup 1.0000x reference)
//
#include <hip/hip_runtime.h>
#include <hip/hip_bf16.h>
#include <stdint.h>
#include <stddef.h>

// DCNv2 forward: B=4, H=W=96, C=256, F=256, K=9 (3x3, same, stride1, dil1), DG=1.
// R4 post-mortem: 96x128 (3.0 blk/CU) fixed imbalance: k_gemm 118->69us. Remaining ~180us
//   is k_sample/k_omgemm/k_pad + cols HBM round-trip (170MB write + 87MB fetch).
// R5: FUSE sampling into the GEMM. k_fused computes the 96x32 sampled A-tile in-LDS per
//   K-step (corner offsets/weights precomputed per (px,k) in LDS, mask folded into weights),
//   B via global_load_lds. cols[] and k_sample are gone. LDS 41.9KB -> 3 blk/CU = grid 768.

namespace {
constexpr int H  = 96, W = 96, C = 256, F = 256;
constexpr int HP = 98;            // padded spatial dim (1-px zero halo)
constexpr int NP = 4 * 96 * 96;   // 36864 output pixels
constexpr int KC = 9 * 256;       // 2304 = GEMM K
}

typedef __attribute__((ext_vector_type(8))) short bf16x8;
typedef __attribute__((ext_vector_type(4))) float floatx4;

__device__ __forceinline__ void load_lds16(const void* g, void* l) {
  __builtin_amdgcn_global_load_lds((const __attribute__((address_space(1))) void*)g,
                                   (__attribute__((address_space(3))) void*)l,
                                   16, 0, 0);
}

__device__ __forceinline__ unsigned short bf16bits(float f) {
  __hip_bfloat16 h = __float2bfloat16(f);
  return *reinterpret_cast<unsigned short*>(&h);
}

// ---------------- k_pad: x fp32 -> xp bf16 with zero halo (4 ch/thread) ----------------
__global__ __launch_bounds__(256) void k_pad(const float* __restrict__ x,
                                             uint2* __restrict__ xp) {
  const int tid = threadIdx.x;
  const int sub = tid >> 6, c4 = tid & 63;
  const int pp  = blockIdx.x * 4 + sub;
  const int b   = pp / (HP * HP);
  const int r   = pp % (HP * HP);
  const int y   = r / HP, xq = r % HP;
  uint2 o = {0u, 0u};
  if (y >= 1 && y <= H && xq >= 1 && xq <= W) {
    const float4 v = *(const float4*)(x + ((size_t)((b * H + (y - 1)) * W + (xq - 1))) * C + c4 * 4);
    o.x = (uint32_t)bf16bits(v.x) | ((uint32_t)bf16bits(v.y) << 16);
    o.y = (uint32_t)bf16bits(v.z) | ((uint32_t)bf16bits(v.w) << 16);
  }
  xp[(size_t)pp * 64 + c4] = o;
}

// ---------------- k_omw: omk [9*256][27] -> wom [32][2304] bf16, zero-pad rows ----------------
__global__ __launch_bounds__(256) void k_omw(const float* __restrict__ omk,
                                             __hip_bfloat16* __restrict__ wom) {
  const int kk = blockIdx.x;
  const int oc = blockIdx.y;
  const int c  = threadIdx.x;
  float v = (oc < 27) ? omk[(size_t)(kk * 256 + c) * 27 + oc] : 0.f;
  wom[(size_t)oc * KC + kk * 256 + c] = __float2bfloat16(v);
}

// ---------------- k_wt: kern [KC][F] fp32 -> wt [F][KC] bf16 via LDS transpose ----------------
__global__ __launch_bounds__(256) void k_wt(const float* __restrict__ kern,
                                            __hip_bfloat16* __restrict__ wt) {
  __shared__ float t[64][65];
  const int kc0 = blockIdx.x * 64, f0 = blockIdx.y * 64;
  const int rr = threadIdx.x >> 6, cc = threadIdx.x & 63;
#pragma unroll
  for (int i = 0; i < 16; ++i) {
    const int row = rr * 16 + i;
    t[row][cc] = kern[(size_t)(kc0 + row) * F + f0 + cc];
  }
  __syncthreads();
#pragma unroll
  for (int i = 0; i < 16; ++i) {
    const int frow = rr * 16 + i;
    wt[(size_t)(f0 + frow) * KC + kc0 + cc] = __float2bfloat16(t[cc][frow]);
  }
}

// ---------------- k_omgemm: implicit-im2col MFMA GEMM, tile 128(M) x 32(N), split-K x6 ----------------
__global__ __launch_bounds__(256) void k_omgemm(const __hip_bfloat16* __restrict__ xp,
                                                const __hip_bfloat16* __restrict__ wom,
                                                float* __restrict__ pOm) {
  __shared__ __align__(16) char lds[10240];
  const int tid  = threadIdx.x;
  const int m0   = blockIdx.x * 128;
  const int s    = blockIdx.y;
  const int lane = tid & 63, wave = tid >> 6;
  const int quad = lane >> 4, l16 = lane & 15;

  const int kp = tid & 3;
  const __hip_bfloat16* abase[2];
#pragma unroll
  for (int j = 0; j < 2; ++j) {
    const int row = (tid >> 2) + j * 64;
    const int p = m0 + row;
    const int b = p / (H * W);
    const int hw = p % (H * W);
    const int h = hw / W, w = hw % W;
    abase[j] = (const __hip_bfloat16*)xp + ((size_t)(b * HP + h) * HP + w) * C + kp * 8;
  }
  const __hip_bfloat16* bbase = wom + (size_t)(tid >> 2) * KC + kp * 8;

  floatx4 acc[2][2];
#pragma unroll
  for (int i = 0; i < 2; ++i)
#pragma unroll
    for (int j = 0; j < 2; ++j) acc[i][j] = (floatx4){0.f, 0.f, 0.f, 0.f};

  const int kbeg = s * 384;
#pragma unroll 1
  for (int k0 = kbeg; k0 < kbeg + 384; k0 += 32) {
    const int kk = k0 >> 8;
    const int c0 = k0 & 255;
    const int kh = kk / 3, kw = kk % 3;
    const int aoff = (kh * HP + kw) * C + c0;

    __syncthreads();
    load_lds16(abase[0] + aoff, &lds[tid * 16]);
    load_lds16(abase[1] + aoff, &lds[4096 + tid * 16]);
    if (tid < 128) load_lds16(bbase + k0, &lds[8192 + tid * 16]);
    __syncthreads();

    bf16x8 af[2], bfr[2];
#pragma unroll
    for (int mt = 0; mt < 2; ++mt)
      af[mt] = *(const bf16x8*)&lds[((wave * 32 + mt * 16 + l16) * 32 + quad * 8) * 2];
#pragma unroll
    for (int nt = 0; nt < 2; ++nt)
      bfr[nt] = *(const bf16x8*)&lds[8192 + ((nt * 16 + l16) * 32 + quad * 8) * 2];
#pragma unroll
    for (int mt = 0; mt < 2; ++mt)
#pragma unroll
      for (int nt = 0; nt < 2; ++nt)
        acc[mt][nt] = __builtin_amdgcn_mfma_f32_16x16x32_bf16(af[mt], bfr[nt], acc[mt][nt], 0, 0, 0);
  }

#pragma unroll
  for (int mt = 0; mt < 2; ++mt)
#pragma unroll
    for (int nt = 0; nt < 2; ++nt) {
      const int gm = m0 + wave * 32 + mt * 16 + quad * 4;
      const int gn = nt * 16 + l16;
#pragma unroll
      for (int r = 0; r < 4; ++r)
        __hip_atomic_fetch_add(&pOm[(size_t)(gm + r) * 32 + gn], acc[mt][nt][r],
                               __ATOMIC_RELAXED, __HIP_MEMORY_SCOPE_AGENT);
    }
}

// ---------------- k_fused: sampling fused into 96(M) x 128(N) MFMA GEMM ----------------
// M-tile = one image row (96 px, same b, same h). Per K-step (kh,kw, 32 ch): 256 threads
// compute the sampled 96x32 bf16 A-tile into LDS (3 units/thread, 4ch each), B via
// global_load_lds. Corner {offset, weight*mask} precomputed per (px,k) in LDS.
__global__ __launch_bounds__(256, 3) void k_fused(const uint2* __restrict__ xpu,
                                                  const float* __restrict__ pOm,
                                                  const float* __restrict__ om_bias,
                                                  const __hip_bfloat16* __restrict__ Bt,
                                                  const float* __restrict__ bias,
                                                  float* __restrict__ out) {
  __shared__ __align__(16) char s_a[6144];    // A tile [96][32] bf16
  __shared__ __align__(16) char s_b[8192];    // B tile [128][32] bf16
  __shared__ __align__(16) float s_ow[96 * 9 * 8];  // per (px,k): {off,w} x4 corners (27648 B)

  const int tid  = threadIdx.x;
  const int m0   = blockIdx.x * 96;
  const int n0   = blockIdx.y * 128;
  const int b    = m0 / (H * W);
  const int h    = (m0 % (H * W)) / W;        // whole tile = row h of image b
  const int lane = tid & 63, wave = tid >> 6;
  const int wm = wave & 1, wn = wave >> 1;    // wave = 48M x 64N
  const int quad = lane >> 4, l16 = lane & 15;

  // ---- setup: offsets/weights for 96 px x 9 k ----
#pragma unroll 1
  for (int i = tid; i < 96 * 9; i += 256) {
    const int wq = i % 96, k = i / 96;
    const int p  = m0 + wq;
    const float dy = om_bias[2 * k]     + pOm[(size_t)p * 32 + 2 * k];
    const float dx = om_bias[2 * k + 1] + pOm[(size_t)p * 32 + 2 * k + 1];
    const float mv = om_bias[18 + k]    + pOm[(size_t)p * 32 + 18 + k];
    const float m  = 2.f / (1.f + __expf(-mv));
    const float sy = (float)(h - 1 + k / 3) + dy;
    const float sx = (float)(wq - 1 + k % 3) + dx;
    const float y0f = floorf(sy), x0f = floorf(sx);
    const float fy = sy - y0f, fx = sx - x0f;
    const int y0 = (int)y0f, x0 = (int)x0f;
    float* ow = &s_ow[(size_t)(wq * 9 + k) * 8];
#pragma unroll
    for (int c2 = 0; c2 < 4; ++c2) {
      const int dy2 = c2 >> 1, dx2 = c2 & 1;
      const int yi = y0 + dy2, xi = x0 + dx2;
      const bool valid = (yi >= 0) & (yi < H) & (xi >= 0) & (xi < W);
      const float wgt = valid ? (dy2 ? fy : 1.f - fy) * (dx2 ? fx : 1.f - fx) * m : 0.f;
      const int yc = min(max(yi + 1, 0), HP - 1);
      const int xc = min(max(xi + 1, 0), HP - 1);
      const int off = ((b * HP + yc) * HP + xc) * 64;   // uint2 units
      ow[c2 * 2]     = __int_as_float(off);
      ow[c2 * 2 + 1] = wgt;
    }
  }

  floatx4 acc[3][4];
#pragma unroll
  for (int i = 0; i < 3; ++i)
#pragma unroll
    for (int j = 0; j < 4; ++j) acc[i][j] = (floatx4){0.f, 0.f, 0.f, 0.f};

#pragma unroll 1
  for (int k0 = 0; k0 < KC; k0 += 32) {
    const int kk = k0 >> 8;           // kernel point 0..8 (32-chunks never straddle)
    const int cb = (k0 & 255) >> 2;   // uint2 channel base 0..63

    __syncthreads();   // prev MFMA reads done; setup s_ow visible on first iter
    {  // B staging (DMA overlaps the sampling VALU below)
      const int row = tid >> 2, kp = tid & 3;
      load_lds16(Bt + (size_t)(n0 + row)      * KC + k0 + kp * 8, &s_b[tid * 16]);
      load_lds16(Bt + (size_t)(n0 + 64 + row) * KC + k0 + kp * 8, &s_b[4096 + tid * 16]);
    }
    // A sampling: 768 units = 96 px x 8 channel-groups (4 ch each); 3 units/thread
#pragma unroll
    for (int u = 0; u < 3; ++u) {
      const int id  = tid + u * 256;
      const int pxl = id >> 3, g = id & 7;
      const float4* owp = (const float4*)&s_ow[(size_t)(pxl * 9 + kk) * 8];
      const float4 ow0 = owp[0], ow1 = owp[1];
      float v0 = 0.f, v1 = 0.f, v2 = 0.f, v3 = 0.f;
      {
        const uint2 v = xpu[(size_t)__float_as_int(ow0.x) + cb + g];
        const float wg = ow0.y;
        v0 += wg * __uint_as_float(v.x << 16); v1 += wg * __uint_as_float(v.x & 0xffff0000u);
        v2 += wg * __uint_as_float(v.y << 16); v3 += wg * __uint_as_float(v.y & 0xffff0000u);
      }
      {
        const uint2 v = xpu[(size_t)__float_as_int(ow0.z) + cb + g];
        const float wg = ow0.w;
        v0 += wg * __uint_as_float(v.x << 16); v1 += wg * __uint_as_float(v.x & 0xffff0000u);
        v2 += wg * __uint_as_float(v.y << 16); v3 += wg * __uint_as_float(v.y & 0xffff0000u);
      }
      {
        const uint2 v = xpu[(size_t)__float_as_int(ow1.x) + cb + g];
        const float wg = ow1.y;
        v0 += wg * __uint_as_float(v.x << 16); v1 += wg * __uint_as_float(v.x & 0xffff0000u);
        v2 += wg * __uint_as_float(v.y << 16); v3 += wg * __uint_as_float(v.y & 0xffff0000u);
      }
      {
        const uint2 v = xpu[(size_t)__float_as_int(ow1.z) + cb + g];
        const float wg = ow1.w;
        v0 += wg * __uint_as_float(v.x << 16); v1 += wg * __uint_as_float(v.x & 0xffff0000u);
        v2 += wg * __uint_as_float(v.y << 16); v3 += wg * __uint_as_float(v.y & 0xffff0000u);
      }
      uint2 o;
      o.x = (uint32_t)bf16bits(v0) | ((uint32_t)bf16bits(v1) << 16);
      o.y = (uint32_t)bf16bits(v2) | ((uint32_t)bf16bits(v3) << 16);
      *(uint2*)&s_a[pxl * 64 + g * 8] = o;
    }
    __syncthreads();   // A ds_writes + B DMA visible

    bf16x8 af[3], bfr[4];
#pragma unroll
    for (int mt = 0; mt < 3; ++mt)
      af[mt] = *(const bf16x8*)&s_a[((wm * 48 + mt * 16 + l16) * 32 + quad * 8) * 2];
#pragma unroll
    for (int nt = 0; nt < 4; ++nt)
      bfr[nt] = *(const bf16x8*)&s_b[((wn * 64 + nt * 16 + l16) * 32 + quad * 8) * 2];
#pragma unroll
    for (int mt = 0; mt < 3; ++mt)
#pragma unroll
      for (int nt = 0; nt < 4; ++nt)
        acc[mt][nt] = __builtin_amdgcn_mfma_f32_16x16x32_bf16(af[mt], bfr[nt], acc[mt][nt], 0, 0, 0);
  }

  // epilogue: C/D layout col=lane&15, row=quad*4+reg, + bias
#pragma unroll
  for (int mt = 0; mt < 3; ++mt) {
#pragma unroll
    for (int nt = 0; nt < 4; ++nt) {
      const int gm = m0 + wm * 48 + mt * 16 + quad * 4;
      const int gn = n0 + wn * 64 + nt * 16 + l16;
      const float bs = bias[gn];
#pragma unroll
      for (int r = 0; r < 4; ++r)
        out[(size_t)(gm + r) * F + gn] = acc[mt][nt][r] + bs;
    }
  }
}

extern "C" void kernel_launch(void* const* d_in, const int* in_sizes, int n_in,
                              void* d_out, int out_size, void* d_ws, size_t ws_size,
                              hipStream_t stream) {
  const float* x    = (const float*)d_in[0];   // [4,96,96,256]
  const float* omk  = (const float*)d_in[1];   // [3,3,256,27]
  const float* omb  = (const float*)d_in[2];   // [27]
  const float* kern = (const float*)d_in[3];   // [2304,256]
  const float* bias = (const float*)d_in[4];   // [256]
  float* out = (float*)d_out;                  // [4,96,96,256]

  char* ws = (char*)d_ws;
  size_t off = 0;
  __hip_bfloat16* wt   = (__hip_bfloat16*)(ws + off); off += (size_t)F * KC * 2;           // 1,179,648
  __hip_bfloat16* xp   = (__hip_bfloat16*)(ws + off); off += (size_t)4 * HP * HP * C * 2;  // 19,668,992
  __hip_bfloat16* wom  = (__hip_bfloat16*)(ws + off); off += (size_t)32 * KC * 2;          // 147,456
  float*          pOm  = (float*)(ws + off);          off += (size_t)NP * 32 * 4;          // 4,718,592

  k_pad   <<<dim3(4 * HP * HP / 4), 256, 0, stream>>>(x, (uint2*)xp);
  k_omw   <<<dim3(9, 32),           256, 0, stream>>>(omk, wom);
  k_wt    <<<dim3(KC / 64, F / 64), 256, 0, stream>>>(kern, wt);
  hipMemsetAsync(pOm, 0, (size_t)NP * 32 * 4, stream);
  k_omgemm<<<dim3(NP / 128, 6),     256, 0, stream>>>(xp, wom, pOm);
  k_fused <<<dim3(NP / 96, F / 128), 256, 0, stream>>>((const uint2*)xp, pOm, omb, wt, bias, out);
}

// Round 6
// 227.527 us; speedup vs baseline: 1.2470x; 1.2470x over previous
//
#include <hip/hip_runtime.h>
#include <hip/hip_bf16.h>
#include <stdint.h>
#include <stddef.h>

// DCNv2 forward: B=4, H=W=96, C=256, F=256, K=9 (3x3, same, stride1, dil1), DG=1.
// R5 post-mortem: fused sampling+GEMM was FETCH-bound (313MB, 2.2TB/s sustained = dur):
//   per-K-step gathers half-use cache lines and sampling was duplicated per N-tile. REVERTED.
// R6: R4 pipeline + (a) k_prep merges pad/omw/wt/pOm-zero into one dispatch (uint4 pad),
//   (b) k_sample rewrite: 8px/block, uint4 full-line gathers, v_cvt_pk_bf16_f32 packing,
//   mask folded into corner weights. k_omgemm/k_gemm unchanged (69us proven).

namespace {
constexpr int H  = 96, W = 96, C = 256, F = 256;
constexpr int HP = 98;            // padded spatial dim (1-px zero halo)
constexpr int NP = 4 * 96 * 96;   // 36864 output pixels
constexpr int KC = 9 * 256;       // 2304 = GEMM K

constexpr int NB_PAD  = 4 * HP * HP / 8;  // 4802 blocks, 8 px each
constexpr int NB_OMW  = 9 * 32;           // 288
constexpr int NB_WT   = (KC / 64) * (F / 64);  // 144
constexpr int NB_ZERO = NP * 32 * 4 / 4096;    // 1152 (float4 x 256 thr)
}

typedef __attribute__((ext_vector_type(8))) short bf16x8;
typedef __attribute__((ext_vector_type(4))) float floatx4;

__device__ __forceinline__ void load_lds16(const void* g, void* l) {
  __builtin_amdgcn_global_load_lds((const __attribute__((address_space(1))) void*)g,
                                   (__attribute__((address_space(3))) void*)l,
                                   16, 0, 0);
}

__device__ __forceinline__ uint32_t pk2(float lo, float hi) {   // v_cvt_pk_bf16_f32 (RNE)
  __hip_bfloat162 t = __float22bfloat162_rn(float2{lo, hi});
  return *reinterpret_cast<uint32_t*>(&t);
}

__device__ __forceinline__ void acc8(uint4 v, float w, float* a) {
  a[0] += w * __uint_as_float(v.x << 16); a[1] += w * __uint_as_float(v.x & 0xffff0000u);
  a[2] += w * __uint_as_float(v.y << 16); a[3] += w * __uint_as_float(v.y & 0xffff0000u);
  a[4] += w * __uint_as_float(v.z << 16); a[5] += w * __uint_as_float(v.z & 0xffff0000u);
  a[6] += w * __uint_as_float(v.w << 16); a[7] += w * __uint_as_float(v.w & 0xffff0000u);
}

// ---------------- k_prep: pad + omw + wt + pOm-zero in one dispatch ----------------
__global__ __launch_bounds__(256) void k_prep(const float* __restrict__ x,
                                              const float* __restrict__ omk,
                                              const float* __restrict__ kern,
                                              uint4* __restrict__ xp4,
                                              __hip_bfloat16* __restrict__ wom,
                                              __hip_bfloat16* __restrict__ wt,
                                              float4* __restrict__ pOmz) {
  __shared__ float t[64][65];
  const int bi = blockIdx.x, tid = threadIdx.x;

  if (bi < NB_PAD) {                       // ---- pad: 8 px/block, 8 ch/thread ----
    const int sub = tid >> 5, cid = tid & 31;
    const int pp  = bi * 8 + sub;
    const int b   = pp / (HP * HP);
    const int r   = pp % (HP * HP);
    const int y   = r / HP, xq = r % HP;
    uint4 o = {0u, 0u, 0u, 0u};
    if (y >= 1 && y <= H && xq >= 1 && xq <= W) {
      const float* src = x + ((size_t)((b * H + (y - 1)) * W + (xq - 1))) * C + cid * 8;
      const float4 v0 = *(const float4*)src;
      const float4 v1 = *(const float4*)(src + 4);
      o.x = pk2(v0.x, v0.y); o.y = pk2(v0.z, v0.w);
      o.z = pk2(v1.x, v1.y); o.w = pk2(v1.z, v1.w);
    }
    xp4[(size_t)pp * 32 + cid] = o;
  } else if (bi < NB_PAD + NB_OMW) {       // ---- omw: [9*256][27] -> [32][2304] ----
    const int i  = bi - NB_PAD;
    const int kk = i / 32, oc = i % 32;
    float v = (oc < 27) ? omk[(size_t)(kk * 256 + tid) * 27 + oc] : 0.f;
    wom[(size_t)oc * KC + kk * 256 + tid] = __float2bfloat16(v);
  } else if (bi < NB_PAD + NB_OMW + NB_WT) {  // ---- wt: [KC][F] -> [F][KC] bf16 ----
    const int j   = bi - NB_PAD - NB_OMW;
    const int kc0 = (j % (KC / 64)) * 64, f0 = (j / (KC / 64)) * 64;
    const int rr = tid >> 6, cc = tid & 63;
#pragma unroll
    for (int i = 0; i < 16; ++i)
      t[rr * 16 + i][cc] = kern[(size_t)(kc0 + rr * 16 + i) * F + f0 + cc];
    __syncthreads();
#pragma unroll
    for (int i = 0; i < 16; ++i) {
      const int frow = rr * 16 + i;
      wt[(size_t)(f0 + frow) * KC + kc0 + cc] = __float2bfloat16(t[cc][frow]);
    }
  } else {                                 // ---- pOm zero ----
    const int j = bi - NB_PAD - NB_OMW - NB_WT;
    pOmz[(size_t)j * 256 + tid] = (float4){0.f, 0.f, 0.f, 0.f};
  }
}

// ---------------- k_omgemm: implicit-im2col MFMA GEMM, 128(M)x32(N), split-K x6 ----------------
__global__ __launch_bounds__(256) void k_omgemm(const __hip_bfloat16* __restrict__ xp,
                                                const __hip_bfloat16* __restrict__ wom,
                                                float* __restrict__ pOm) {
  __shared__ __align__(16) char lds[10240];
  const int tid  = threadIdx.x;
  const int m0   = blockIdx.x * 128;
  const int s    = blockIdx.y;
  const int lane = tid & 63, wave = tid >> 6;
  const int quad = lane >> 4, l16 = lane & 15;

  const int kp = tid & 3;
  const __hip_bfloat16* abase[2];
#pragma unroll
  for (int j = 0; j < 2; ++j) {
    const int row = (tid >> 2) + j * 64;
    const int p = m0 + row;
    const int b = p / (H * W);
    const int hw = p % (H * W);
    const int h = hw / W, w = hw % W;
    abase[j] = xp + ((size_t)(b * HP + h) * HP + w) * C + kp * 8;
  }
  const __hip_bfloat16* bbase = wom + (size_t)(tid >> 2) * KC + kp * 8;

  floatx4 acc[2][2];
#pragma unroll
  for (int i = 0; i < 2; ++i)
#pragma unroll
    for (int j = 0; j < 2; ++j) acc[i][j] = (floatx4){0.f, 0.f, 0.f, 0.f};

  const int kbeg = s * 384;
#pragma unroll 1
  for (int k0 = kbeg; k0 < kbeg + 384; k0 += 32) {
    const int kk = k0 >> 8;
    const int c0 = k0 & 255;
    const int kh = kk / 3, kw = kk % 3;
    const int aoff = (kh * HP + kw) * C + c0;

    __syncthreads();
    load_lds16(abase[0] + aoff, &lds[tid * 16]);
    load_lds16(abase[1] + aoff, &lds[4096 + tid * 16]);
    if (tid < 128) load_lds16(bbase + k0, &lds[8192 + tid * 16]);
    __syncthreads();

    bf16x8 af[2], bfr[2];
#pragma unroll
    for (int mt = 0; mt < 2; ++mt)
      af[mt] = *(const bf16x8*)&lds[((wave * 32 + mt * 16 + l16) * 32 + quad * 8) * 2];
#pragma unroll
    for (int nt = 0; nt < 2; ++nt)
      bfr[nt] = *(const bf16x8*)&lds[8192 + ((nt * 16 + l16) * 32 + quad * 8) * 2];
#pragma unroll
    for (int mt = 0; mt < 2; ++mt)
#pragma unroll
      for (int nt = 0; nt < 2; ++nt)
        acc[mt][nt] = __builtin_amdgcn_mfma_f32_16x16x32_bf16(af[mt], bfr[nt], acc[mt][nt], 0, 0, 0);
  }

#pragma unroll
  for (int mt = 0; mt < 2; ++mt)
#pragma unroll
    for (int nt = 0; nt < 2; ++nt) {
      const int gm = m0 + wave * 32 + mt * 16 + quad * 4;
      const int gn = nt * 16 + l16;
#pragma unroll
      for (int r = 0; r < 4; ++r)
        __hip_atomic_fetch_add(&pOm[(size_t)(gm + r) * 32 + gn], acc[mt][nt][r],
                               __ATOMIC_RELAXED, __HIP_MEMORY_SCOPE_AGENT);
    }
}

// ---------------- k_sample: 8 px/block, 8 ch/thread via uint4 full-line gathers ----------------
__global__ __launch_bounds__(256) void k_sample(const uint4* __restrict__ xp4,
                                                const float* __restrict__ pOm,
                                                const float* __restrict__ om_bias,
                                                uint4* __restrict__ cols4) {
  __shared__ float2 s_ow[8][9][4];   // per (px,k,corner): {uint4-offset, weight*mask}

  const int tid = threadIdx.x;
  const int sub = tid >> 5, cid = tid & 31;     // px-in-block, 8-ch unit

  if (tid < 72) {                               // setup: 8 px x 9 k
    const int ps = tid / 9, k = tid % 9;
    const int p  = blockIdx.x * 8 + ps;
    const int b  = p / (H * W);
    const int hw = p % (H * W);
    const int h = hw / W, w = hw % W;
    const float dy = om_bias[2 * k]     + pOm[(size_t)p * 32 + 2 * k];
    const float dx = om_bias[2 * k + 1] + pOm[(size_t)p * 32 + 2 * k + 1];
    const float mv = om_bias[18 + k]    + pOm[(size_t)p * 32 + 18 + k];
    const float m  = 2.f / (1.f + __expf(-mv));
    const float sy = (float)(h - 1 + k / 3) + dy;
    const float sx = (float)(w - 1 + k % 3) + dx;
    const float y0f = floorf(sy), x0f = floorf(sx);
    const float fy = sy - y0f, fx = sx - x0f;
    const int y0 = (int)y0f, x0 = (int)x0f;
#pragma unroll
    for (int c2 = 0; c2 < 4; ++c2) {
      const int dy2 = c2 >> 1, dx2 = c2 & 1;
      const int yi = y0 + dy2, xi = x0 + dx2;
      const bool valid = (yi >= 0) & (yi < H) & (xi >= 0) & (xi < W);
      const float wgt = valid ? (dy2 ? fy : 1.f - fy) * (dx2 ? fx : 1.f - fx) * m : 0.f;
      const int yc = min(max(yi + 1, 0), HP - 1);
      const int xc = min(max(xi + 1, 0), HP - 1);
      const int off = ((b * HP + yc) * HP + xc) * 32;   // uint4 units
      s_ow[ps][k][c2] = float2{__int_as_float(off), wgt};
    }
  }
  __syncthreads();

  const int p = blockIdx.x * 8 + sub;
  uint4* __restrict__ ob = cols4 + (size_t)p * 288 + cid;   // KC bf16 = 288 uint4/row

#pragma unroll 1
  for (int k = 0; k < 9; ++k) {
    const float2 ow0 = s_ow[sub][k][0], ow1 = s_ow[sub][k][1];
    const float2 ow2 = s_ow[sub][k][2], ow3 = s_ow[sub][k][3];
    float a[8] = {0.f, 0.f, 0.f, 0.f, 0.f, 0.f, 0.f, 0.f};
    acc8(xp4[(size_t)__float_as_int(ow0.x) + cid], ow0.y, a);
    acc8(xp4[(size_t)__float_as_int(ow1.x) + cid], ow1.y, a);
    acc8(xp4[(size_t)__float_as_int(ow2.x) + cid], ow2.y, a);
    acc8(xp4[(size_t)__float_as_int(ow3.x) + cid], ow3.y, a);
    uint4 o;
    o.x = pk2(a[0], a[1]); o.y = pk2(a[2], a[3]);
    o.z = pk2(a[4], a[5]); o.w = pk2(a[6], a[7]);
    ob[k * 32] = o;
  }
}

// ---------------- k_gemm: bf16 MFMA GEMM, 96(M) x 128(N) tile, 768 blocks = 3.0/CU ----------------
__global__ __launch_bounds__(256) void k_gemm(const __hip_bfloat16* __restrict__ A,
                                              const __hip_bfloat16* __restrict__ Bt,
                                              const float* __restrict__ bias,
                                              float* __restrict__ out) {
  __shared__ __align__(16) char lds[14336];   // A [96][32] @0 (6KB), B [128][32] @6144 (8KB)

  const int tid  = threadIdx.x;
  const int m0   = blockIdx.x * 96;
  const int n0   = blockIdx.y * 128;
  const int lane = tid & 63, wave = tid >> 6;
  const int wm = wave & 1, wn = wave >> 1;    // wave = 48M x 64N
  const int quad = lane >> 4, l16 = lane & 15;

  floatx4 acc[3][4];
#pragma unroll
  for (int i = 0; i < 3; ++i)
#pragma unroll
    for (int j = 0; j < 4; ++j) acc[i][j] = (floatx4){0.f, 0.f, 0.f, 0.f};

#pragma unroll 1
  for (int k0 = 0; k0 < KC; k0 += 32) {
    __syncthreads();
    {
      const int row = tid >> 2, kp = tid & 3;
      load_lds16(A + (size_t)(m0 + row) * KC + k0 + kp * 8, &lds[tid * 16]);
      if (tid < 128)
        load_lds16(A + (size_t)(m0 + 64 + row) * KC + k0 + kp * 8, &lds[4096 + tid * 16]);
      load_lds16(Bt + (size_t)(n0 + row) * KC + k0 + kp * 8, &lds[6144 + tid * 16]);
      load_lds16(Bt + (size_t)(n0 + 64 + row) * KC + k0 + kp * 8, &lds[10240 + tid * 16]);
    }
    __syncthreads();

    bf16x8 af[3], bfr[4];
#pragma unroll
    for (int mt = 0; mt < 3; ++mt)
      af[mt] = *(const bf16x8*)&lds[((wm * 48 + mt * 16 + l16) * 32 + quad * 8) * 2];
#pragma unroll
    for (int nt = 0; nt < 4; ++nt)
      bfr[nt] = *(const bf16x8*)&lds[6144 + ((wn * 64 + nt * 16 + l16) * 32 + quad * 8) * 2];
#pragma unroll
    for (int mt = 0; mt < 3; ++mt)
#pragma unroll
      for (int nt = 0; nt < 4; ++nt)
        acc[mt][nt] = __builtin_amdgcn_mfma_f32_16x16x32_bf16(af[mt], bfr[nt], acc[mt][nt], 0, 0, 0);
  }

#pragma unroll
  for (int mt = 0; mt < 3; ++mt) {
#pragma unroll
    for (int nt = 0; nt < 4; ++nt) {
      const int gm = m0 + wm * 48 + mt * 16 + quad * 4;
      const int gn = n0 + wn * 64 + nt * 16 + l16;
      const float bs = bias[gn];
#pragma unroll
      for (int r = 0; r < 4; ++r)
        out[(size_t)(gm + r) * F + gn] = acc[mt][nt][r] + bs;
    }
  }
}

extern "C" void kernel_launch(void* const* d_in, const int* in_sizes, int n_in,
                              void* d_out, int out_size, void* d_ws, size_t ws_size,
                              hipStream_t stream) {
  const float* x    = (const float*)d_in[0];   // [4,96,96,256]
  const float* omk  = (const float*)d_in[1];   // [3,3,256,27]
  const float* omb  = (const float*)d_in[2];   // [27]
  const float* kern = (const float*)d_in[3];   // [2304,256]
  const float* bias = (const float*)d_in[4];   // [256]
  float* out = (float*)d_out;                  // [4,96,96,256]

  char* ws = (char*)d_ws;
  size_t off = 0;
  __hip_bfloat16* wt   = (__hip_bfloat16*)(ws + off); off += (size_t)F * KC * 2;           // 1,179,648
  __hip_bfloat16* xp   = (__hip_bfloat16*)(ws + off); off += (size_t)4 * HP * HP * C * 2;  // 19,668,992
  __hip_bfloat16* wom  = (__hip_bfloat16*)(ws + off); off += (size_t)32 * KC * 2;          // 147,456
  float*          pOm  = (float*)(ws + off);          off += (size_t)NP * 32 * 4;          // 4,718,592
  __hip_bfloat16* cols = (__hip_bfloat16*)(ws + off);                                      // 169,869,312

  k_prep  <<<dim3(NB_PAD + NB_OMW + NB_WT + NB_ZERO), 256, 0, stream>>>(
      x, omk, kern, (uint4*)xp, wom, wt, (float4*)pOm);
  k_omgemm<<<dim3(NP / 128, 6),      256, 0, stream>>>(xp, wom, pOm);
  k_sample<<<dim3(NP / 8),           256, 0, stream>>>((const uint4*)xp, pOm, omb, (uint4*)cols);
  k_gemm  <<<dim3(NP / 96, F / 128), 256, 0, stream>>>(cols, wt, bias, out);
}